// Round 2
// baseline (45867.480 us; speedup 1.0000x reference)
//
#include <hip/hip_runtime.h>
#include <hip/hip_bf16.h>
#include <hip/hip_cooperative_groups.h>

namespace cg = cooperative_groups;

#define B 32
#define S 512
#define H 1024
#define G 4096          // 4*H

typedef __attribute__((ext_vector_type(8))) short bf16x8;
typedef __attribute__((ext_vector_type(8))) unsigned short u16x8;
typedef __attribute__((ext_vector_type(4))) float f32x4;

__device__ __forceinline__ unsigned short f2bf(float v) {
    __hip_bfloat16 b = __float2bfloat16(v);
    return *reinterpret_cast<unsigned short*>(&b);
}

// =====================================================================
// prep_weights: build fragment-ordered bf16 weight buffer.
// Combined K = 2048: kk in [0,1024) -> W[kk][g], kk in [1024,2048) -> U[kk-1024][g].
// Layout: chunk index idx = ((blk*8 + w)*16 + ks*2 + ct)*64 + lane, 8 bf16 per chunk.
//   blk = dir*128 + jg (jg owns j = jg*8 .. jg*8+7, cols c=0..31 with g=(c>>3)*H + jg*8 + (c&7))
//   frag element i: kk = w*256 + ks*32 + (lane>>4)*8 + i, col c = ct*16 + (lane&15)
// =====================================================================
__global__ __launch_bounds__(256)
void prep_weights(const float* __restrict__ Wfw, const float* __restrict__ Ufw,
                  const float* __restrict__ Wbw, const float* __restrict__ Ubw,
                  unsigned short* __restrict__ wbuf)
{
    size_t idx = (size_t)blockIdx.x * 256 + threadIdx.x;   // 2,097,152 chunks
    int lane = idx & 63;
    int ct   = (idx >> 6) & 1;
    int ks   = (idx >> 7) & 7;
    int w    = (idx >> 10) & 7;
    int blk  = (int)(idx >> 13);
    int dir  = blk >> 7, jg = blk & 127;

    int c = ct * 16 + (lane & 15);
    int g = (c >> 3) * H + jg * 8 + (c & 7);
    int kk = w * 256 + ks * 32 + ((lane >> 4) * 8);

    const float* Wsrc = dir ? Wbw : Wfw;
    const float* Usrc = dir ? Ubw : Ufw;

    u16x8 out;
#pragma unroll
    for (int i = 0; i < 8; ++i) {
        int k2 = kk + i;
        float v = (k2 < 1024) ? Wsrc[(size_t)k2 * G + g]
                              : Usrc[(size_t)(k2 - 1024) * G + g];
        out[i] = f2bf(v);
    }
    *(u16x8*)&wbuf[idx * 8] = out;
}

// =====================================================================
// prep_x: x fp32 -> bf16, 16,777,216 elements, 8 per thread
// =====================================================================
__global__ __launch_bounds__(256)
void prep_x(const float* __restrict__ x, unsigned short* __restrict__ xbf)
{
    size_t i8 = ((size_t)blockIdx.x * 256 + threadIdx.x) * 8;
    float4 v0 = *(const float4*)&x[i8];
    float4 v1 = *(const float4*)&x[i8 + 4];
    u16x8 out;
    out[0] = f2bf(v0.x); out[1] = f2bf(v0.y); out[2] = f2bf(v0.z); out[3] = f2bf(v0.w);
    out[4] = f2bf(v1.x); out[5] = f2bf(v1.y); out[6] = f2bf(v1.z); out[7] = f2bf(v1.w);
    *(u16x8*)&xbf[i8] = out;
}

// =====================================================================
// lstm_persist: cooperative persistent kernel.
// Grid 256 blocks x 512 threads (8 waves). Block = (dir, jg) owns 8 j-units
// = 32 gate-cols. Weights (128 KB bf16) live in VGPRs (16 frags/lane).
// Per step: wave w computes K-slice [w*256,(w+1)*256) of combined K=2048
// (x@W for w<4, h@U for w>=4) into a 32x32 fp32 tile; 8-way LDS reduce;
// 256 gate threads update register-resident c/h, write out + h_bf16;
// grid.sync().
// =====================================================================
__global__ __launch_bounds__(512)
void lstm_persist(const unsigned short* __restrict__ wbuf,
                  const unsigned short* __restrict__ xbf,
                  unsigned short* __restrict__ hbf,
                  const float* __restrict__ pad,
                  const float* __restrict__ bfw, const float* __restrict__ bbw,
                  float* __restrict__ dout)
{
    const int blk = blockIdx.x;        // 0..255
    const int dir = blk >> 7;
    const int jg  = blk & 127;
    const int j0  = jg * 8;
    const int tid = threadIdx.x;
    const int wave = tid >> 6;
    const int lane = tid & 63;

    __shared__ float red[8][2][16][33];   // [wave][btile][row(batch%16)][col c] padded

    // ---- load 16 weight fragments into registers (once) ----
    bf16x8 wf[16];
    {
        const unsigned short* base = wbuf + (((size_t)blk * 8 + wave) * 16) * 512 + lane * 8;
#pragma unroll
        for (int f = 0; f < 16; ++f)
            wf[f] = *(const bf16x8*)(base + f * 512);
    }

    // ---- gate-thread constants / state ----
    const int gb = tid & 31;           // batch
    const int gj = (tid >> 5) & 7;     // j within unit (only meaningful tid<256)
    const float* bsrc = dir ? bbw : bfw;
    float biasr[4];
#pragma unroll
    for (int q = 0; q < 4; ++q) biasr[q] = bsrc[q * H + j0 + gj];
    float cst = 0.f, hst = 0.f;

    const int arow  = lane & 15;
    const int akoff = (lane >> 4) * 8;

    cg::grid_group grid = cg::this_grid();

    for (int t = 0; t < S; ++t) {
        const int s = dir ? (S - 1 - t) : t;

        // ---- MFMA phase: 32x32 out tile for this wave's K-slice ----
        const unsigned short* A0;
        size_t rowstride;
        if (wave < 4) {
            A0 = xbf + ((size_t)arow * S + s) * H + wave * 256 + akoff;
            rowstride = (size_t)16 * S * H;
        } else {
            A0 = hbf + ((size_t)dir * B + arow) * H + (wave - 4) * 256 + akoff;
            rowstride = (size_t)16 * H;
        }

        f32x4 acc00 = {0.f,0.f,0.f,0.f}, acc01 = {0.f,0.f,0.f,0.f};
        f32x4 acc10 = {0.f,0.f,0.f,0.f}, acc11 = {0.f,0.f,0.f,0.f};
#pragma unroll
        for (int ks = 0; ks < 8; ++ks) {
            bf16x8 a0 = *(const bf16x8*)(A0 + ks * 32);
            bf16x8 a1 = *(const bf16x8*)(A0 + rowstride + ks * 32);
            acc00 = __builtin_amdgcn_mfma_f32_16x16x32_bf16(a0, wf[ks*2+0], acc00, 0, 0, 0);
            acc01 = __builtin_amdgcn_mfma_f32_16x16x32_bf16(a0, wf[ks*2+1], acc01, 0, 0, 0);
            acc10 = __builtin_amdgcn_mfma_f32_16x16x32_bf16(a1, wf[ks*2+0], acc10, 0, 0, 0);
            acc11 = __builtin_amdgcn_mfma_f32_16x16x32_bf16(a1, wf[ks*2+1], acc11, 0, 0, 0);
        }

        // ---- write partials: D layout col=lane&15, row=(lane>>4)*4+reg ----
        const int drow = (lane >> 4) * 4;
        const int dcol = lane & 15;
#pragma unroll
        for (int r = 0; r < 4; ++r) {
            red[wave][0][drow + r][dcol     ] = acc00[r];
            red[wave][0][drow + r][16 + dcol] = acc01[r];
            red[wave][1][drow + r][dcol     ] = acc10[r];
            red[wave][1][drow + r][16 + dcol] = acc11[r];
        }
        __syncthreads();

        // ---- gate phase: 256 threads, one (b, j) cell each ----
        if (tid < 256) {
            float z[4];
#pragma unroll
            for (int q = 0; q < 4; ++q) {
                int c = q * 8 + gj;
                float zz = biasr[q];
#pragma unroll
                for (int w = 0; w < 8; ++w)
                    zz += red[w][gb >> 4][gb & 15][c];
                z[q] = zz;
            }
            float ig = 1.f / (1.f + expf(-z[0]));
            float fg = 1.f / (1.f + expf(-z[1]));
            float gg = tanhf(z[2]);
            float og = 1.f / (1.f + expf(-z[3]));

            float m  = 1.f - pad[gb * S + s];
            float cn = fg * cst + ig * gg;
            float hn = og * tanhf(cn);
            float h2 = fmaf(m, hn - hst, hst);
            float c2 = fmaf(m, cn - cst, cst);
            hst = h2; cst = c2;

            dout[((size_t)gb * S + s) * (2 * H) + dir * H + j0 + gj] = h2;
            hbf[((size_t)dir * B + gb) * H + j0 + gj] = f2bf(h2);

            if (t == S - 1) {
                size_t base = (size_t)B * S * 2 * H;
                dout[base + dir * 2 * B * H + gb * H + j0 + gj] = h2;            // h
                dout[base + dir * 2 * B * H + B * H + gb * H + j0 + gj] = c2;    // c
            }
        }
        __threadfence();
        grid.sync();
    }
}

// =====================================================================
// Host side
// =====================================================================
extern "C" void kernel_launch(void* const* d_in, const int* in_sizes, int n_in,
                              void* d_out, int out_size, void* d_ws, size_t ws_size,
                              hipStream_t stream)
{
    const float* x   = (const float*)d_in[0];
    const float* pad = (const float*)d_in[1];
    const float* Wfw = (const float*)d_in[2];
    const float* Ufw = (const float*)d_in[3];
    const float* bfw = (const float*)d_in[4];
    const float* Wbw = (const float*)d_in[5];
    const float* Ubw = (const float*)d_in[6];
    const float* bbw = (const float*)d_in[7];
    float* out = (float*)d_out;

    char* w = (char*)d_ws;
    unsigned short* wbuf = (unsigned short*)w;                         // 2*2048*4096 = 16,777,216 elems
    unsigned short* xbf  = wbuf + (size_t)2 * 2048 * 4096;             // 16,777,216 elems
    unsigned short* hbf  = xbf + (size_t)B * S * H;                    // 2*B*H = 65,536 elems

    // h state (bf16 published copy) starts at zero
    hipMemsetAsync(hbf, 0, (size_t)2 * B * H * sizeof(unsigned short), stream);

    prep_weights<<<8192, 256, 0, stream>>>(Wfw, Ufw, Wbw, Ubw, wbuf);
    prep_x<<<8192, 256, 0, stream>>>(x, xbf);

    void* args[] = { (void*)&wbuf, (void*)&xbf, (void*)&hbf, (void*)&pad,
                     (void*)&bfw, (void*)&bbw, (void*)&out };
    hipLaunchCooperativeKernel((void*)lstm_persist, dim3(256), dim3(512),
                               args, 0, stream);
}

// Round 3
// 5383.942 us; speedup vs baseline: 8.5193x; 8.5193x over previous
//
#include <hip/hip_runtime.h>
#include <hip/hip_bf16.h>

#define B 32
#define S 512
#define H 1024
#define G 4096          // 4*H

typedef __attribute__((ext_vector_type(8))) short bf16x8;
typedef __attribute__((ext_vector_type(8))) unsigned short u16x8;
typedef __attribute__((ext_vector_type(4))) float f32x4;

__device__ __forceinline__ unsigned short f2bf(float v) {
    __hip_bfloat16 b = __float2bfloat16(v);
    return *reinterpret_cast<unsigned short*>(&b);
}

// =====================================================================
// prep_weights: build fragment-ordered bf16 weight buffer (combined K=2048:
// kk<1024 -> W[kk][g], else U[kk-1024][g]).
// chunk idx = ((blk*8 + w)*16 + ks*2 + ct)*64 + lane, 8 bf16 per chunk.
//   blk = dir*128 + jg, cols c=0..31 with g=(c>>3)*H + jg*8 + (c&7)
//   frag elem i: kk = w*256 + ks*32 + (lane>>4)*8 + i, col c = ct*16 + (lane&15)
// =====================================================================
__global__ __launch_bounds__(256)
void prep_weights(const float* __restrict__ Wfw, const float* __restrict__ Ufw,
                  const float* __restrict__ Wbw, const float* __restrict__ Ubw,
                  unsigned short* __restrict__ wbuf)
{
    size_t idx = (size_t)blockIdx.x * 256 + threadIdx.x;   // 2,097,152 chunks
    int lane = idx & 63;
    int ct   = (idx >> 6) & 1;
    int ks   = (idx >> 7) & 7;
    int w    = (idx >> 10) & 7;
    int blk  = (int)(idx >> 13);
    int dir  = blk >> 7, jg = blk & 127;

    int c = ct * 16 + (lane & 15);
    int g = (c >> 3) * H + jg * 8 + (c & 7);
    int kk = w * 256 + ks * 32 + ((lane >> 4) * 8);

    const float* Wsrc = dir ? Wbw : Wfw;
    const float* Usrc = dir ? Ubw : Ufw;

    u16x8 out;
#pragma unroll
    for (int i = 0; i < 8; ++i) {
        int k2 = kk + i;
        float v = (k2 < 1024) ? Wsrc[(size_t)k2 * G + g]
                              : Usrc[(size_t)(k2 - 1024) * G + g];
        out[i] = f2bf(v);
    }
    *(u16x8*)&wbuf[idx * 8] = out;
}

// =====================================================================
// prep_x: x fp32 -> bf16
// =====================================================================
__global__ __launch_bounds__(256)
void prep_x(const float* __restrict__ x, unsigned short* __restrict__ xbf)
{
    size_t i8 = ((size_t)blockIdx.x * 256 + threadIdx.x) * 8;
    float4 v0 = *(const float4*)&x[i8];
    float4 v1 = *(const float4*)&x[i8 + 4];
    u16x8 out;
    out[0] = f2bf(v0.x); out[1] = f2bf(v0.y); out[2] = f2bf(v0.z); out[3] = f2bf(v0.w);
    out[4] = f2bf(v1.x); out[5] = f2bf(v1.y); out[6] = f2bf(v1.z); out[7] = f2bf(v1.w);
    *(u16x8*)&xbf[i8] = out;
}

// =====================================================================
// lstm_step: ONE time step. 256 blocks x 512 threads (8 waves).
// Block = (dir, jg) owns 32 gate-cols. Wave w computes K-slice
// [w*256,(w+1)*256) of combined K=2048 (x@W for w<4, h@U for w>=4)
// into a 32x32 fp32 tile; 8-way LDS reduce; 256 gate threads update
// global fp32 c/h state, write encoder out + bf16 h.
// =====================================================================
__global__ __launch_bounds__(512)
void lstm_step(const unsigned short* __restrict__ wbuf,
               const unsigned short* __restrict__ xbf,
               unsigned short* __restrict__ hbf,
               float* __restrict__ hstate, float* __restrict__ cstate,
               const float* __restrict__ pad,
               const float* __restrict__ bfw, const float* __restrict__ bbw,
               float* __restrict__ dout, int t)
{
    const int blk = blockIdx.x;        // 0..255
    const int dir = blk >> 7;
    const int jg  = blk & 127;
    const int j0  = jg * 8;
    const int tid = threadIdx.x;
    const int wave = tid >> 6;
    const int lane = tid & 63;
    const int s = dir ? (S - 1 - t) : t;

    __shared__ float red[8][2][16][33];   // [wave][btile][row(b%16)][col]

    // ---- weight fragments for this step (streamed, L2/L3-resident) ----
    bf16x8 wf[16];
    {
        const unsigned short* base = wbuf + (((size_t)blk * 8 + wave) * 16) * 512 + lane * 8;
#pragma unroll
        for (int f = 0; f < 16; ++f)
            wf[f] = *(const bf16x8*)(base + f * 512);
    }

    // ---- A operand pointers ----
    const int arow  = lane & 15;
    const int akoff = (lane >> 4) * 8;
    const unsigned short* A0;
    size_t rowstride;
    if (wave < 4) {
        A0 = xbf + ((size_t)arow * S + s) * H + wave * 256 + akoff;
        rowstride = (size_t)16 * S * H;
    } else {
        A0 = hbf + ((size_t)dir * B + arow) * H + (wave - 4) * 256 + akoff;
        rowstride = (size_t)16 * H;
    }

    f32x4 acc00 = {0.f,0.f,0.f,0.f}, acc01 = {0.f,0.f,0.f,0.f};
    f32x4 acc10 = {0.f,0.f,0.f,0.f}, acc11 = {0.f,0.f,0.f,0.f};
#pragma unroll
    for (int ks = 0; ks < 8; ++ks) {
        bf16x8 a0 = *(const bf16x8*)(A0 + ks * 32);
        bf16x8 a1 = *(const bf16x8*)(A0 + rowstride + ks * 32);
        acc00 = __builtin_amdgcn_mfma_f32_16x16x32_bf16(a0, wf[ks*2+0], acc00, 0, 0, 0);
        acc01 = __builtin_amdgcn_mfma_f32_16x16x32_bf16(a0, wf[ks*2+1], acc01, 0, 0, 0);
        acc10 = __builtin_amdgcn_mfma_f32_16x16x32_bf16(a1, wf[ks*2+0], acc10, 0, 0, 0);
        acc11 = __builtin_amdgcn_mfma_f32_16x16x32_bf16(a1, wf[ks*2+1], acc11, 0, 0, 0);
    }

    // ---- write partials: D layout col=lane&15, row=(lane>>4)*4+reg ----
    const int drow = (lane >> 4) * 4;
    const int dcol = lane & 15;
#pragma unroll
    for (int r = 0; r < 4; ++r) {
        red[wave][0][drow + r][dcol     ] = acc00[r];
        red[wave][0][drow + r][16 + dcol] = acc01[r];
        red[wave][1][drow + r][dcol     ] = acc10[r];
        red[wave][1][drow + r][16 + dcol] = acc11[r];
    }
    __syncthreads();

    // ---- gate phase: 256 threads, one (b, j) cell each ----
    if (tid < 256) {
        const int gb = tid & 31;
        const int gj = (tid >> 5) & 7;
        const float* bsrc = dir ? bbw : bfw;

        float z[4];
#pragma unroll
        for (int q = 0; q < 4; ++q) {
            int c = q * 8 + gj;
            float zz = bsrc[q * H + j0 + gj];
#pragma unroll
            for (int w = 0; w < 8; ++w)
                zz += red[w][gb >> 4][gb & 15][c];
            z[q] = zz;
        }
        float ig = 1.f / (1.f + expf(-z[0]));
        float fg = 1.f / (1.f + expf(-z[1]));
        float gg = tanhf(z[2]);
        float og = 1.f / (1.f + expf(-z[3]));

        const int hidx = dir * B * H + gb * H + j0 + gj;
        float hst = hstate[hidx], cst = cstate[hidx];

        float m  = 1.f - pad[gb * S + s];
        float cn = fg * cst + ig * gg;
        float hn = og * tanhf(cn);
        float h2 = fmaf(m, hn - hst, hst);
        float c2 = fmaf(m, cn - cst, cst);
        hstate[hidx] = h2;
        cstate[hidx] = c2;
        hbf[hidx] = f2bf(h2);

        dout[((size_t)gb * S + s) * (2 * H) + dir * H + j0 + gj] = h2;

        if (t == S - 1) {
            size_t base = (size_t)B * S * 2 * H;
            dout[base + dir * 2 * B * H + gb * H + j0 + gj] = h2;            // h
            dout[base + dir * 2 * B * H + B * H + gb * H + j0 + gj] = c2;    // c
        }
    }
}

// =====================================================================
// Host side
// =====================================================================
extern "C" void kernel_launch(void* const* d_in, const int* in_sizes, int n_in,
                              void* d_out, int out_size, void* d_ws, size_t ws_size,
                              hipStream_t stream)
{
    const float* x   = (const float*)d_in[0];
    const float* pad = (const float*)d_in[1];
    const float* Wfw = (const float*)d_in[2];
    const float* Ufw = (const float*)d_in[3];
    const float* bfw = (const float*)d_in[4];
    const float* Wbw = (const float*)d_in[5];
    const float* Ubw = (const float*)d_in[6];
    const float* bbw = (const float*)d_in[7];
    float* out = (float*)d_out;

    char* w = (char*)d_ws;
    unsigned short* wbuf = (unsigned short*)w;                     // 16,777,216 shorts (32 MB)
    unsigned short* xbf  = wbuf + (size_t)2 * 2048 * G;            // 16,777,216 shorts (32 MB)
    unsigned short* hbf  = xbf + (size_t)B * S * H;                // 65,536 shorts (128 KB)
    float* hstate = (float*)(hbf + (size_t)2 * B * H);             // 65,536 f (256 KB)
    float* cstate = hstate + (size_t)2 * B * H;                    // 65,536 f (256 KB)

    // zero h (bf16), hstate, cstate in one contiguous memset (640 KB)
    hipMemsetAsync(hbf, 0,
                   (size_t)2 * B * H * sizeof(unsigned short) +
                   (size_t)2 * 2 * B * H * sizeof(float), stream);

    prep_weights<<<8192, 256, 0, stream>>>(Wfw, Ufw, Wbw, Ubw, wbuf);
    prep_x<<<8192, 256, 0, stream>>>(x, xbf);

    for (int t = 0; t < S; ++t)
        lstm_step<<<dim3(256), dim3(512), 0, stream>>>(wbuf, xbf, hbf, hstate, cstate,
                                                       pad, bfw, bbw, out, t);
}